// Round 9
// baseline (114.650 us; speedup 1.0000x reference)
//
#include <hip/hip_runtime.h>

#define N_NODES 10000
#define N_EDGES 640000
#define D       128

#define GEMM_BLOCKS 157            // ceil(10000/64), 64-row M-tile
#define HB          64             // localhist chunks
#define NBLK        (GEMM_BLOCKS + HB)
#define CHUNK       10000          // edges per chunk (64*10000 = 640000)
#define PAD         256            // padded CSR bucket (max deg ~64+6sd << 256)

// pack two fp32 -> two bf16 (RNE) in one uint (low = a, high = b)
__device__ inline unsigned bf16pair(float a, float b) {
    unsigned ua = __float_as_uint(a), ub = __float_as_uint(b);
    ua = (ua + 0x7fffu + ((ua >> 16) & 1u)) >> 16;
    ub = (ub + 0x7fffu + ((ub >> 16) & 1u)) >> 16;
    return ua | (ub << 16);
}

union FusedSmem {
    float As[64][132];    // gemm A-tile (33.8 KB); 4-row/thread read is 2-way
                          // bank-aliased only (rows {i,4+i,8+i,12+i} mod 8
                          // pair up) -> free per m136
    int   cnt[N_NODES];   // hist counters (40 KB)
};

// ---------------------------------------------------------------------------
// Kernel 1 (fused): blocks [0,157) -> Y = nodes @ W stored bf16.
// 64-row tile, 4 rows x 8 cols per thread. Rationale (R7/R8 ledger): GEMM is
// W-fetch-bound — 32-row tiles stream 313 MB of W through L2 (~10 us);
// 64-row tiles halve that (157 MB ~ 4.5 us) while VALU issue (4096 FMA x
// 2cyc ~ 3.4 us) stays below it. R7 proved the converse direction (-rows =
// +8 us). Blocks [157,221) -> LDS local histogram + packing (R0-verified).
// pack[e] = sender(14b) | receiver(14b)<<14 | lrank(4b)<<28.
// ---------------------------------------------------------------------------
__global__ __launch_bounds__(256) void gemm_hist_kernel(const float* __restrict__ nodes,
                                                        const float* __restrict__ Wm,
                                                        unsigned* __restrict__ Yb,
                                                        const int* __restrict__ senders,
                                                        const int* __restrict__ receivers,
                                                        unsigned* __restrict__ pack,
                                                        int* __restrict__ bcnt) {
    __shared__ FusedSmem sm;
    const int t = threadIdx.x;

    if (blockIdx.x < GEMM_BLOCKS) {
        const int row0 = blockIdx.x * 64;

        // stage 64 rows x 128 cols (32 float4/row); 2048 float4 / 256 thr = 8 ea
        for (int i = t; i < 2048; i += 256) {
            int r  = i >> 5;
            int c  = i & 31;
            int gr = row0 + r;
            float4 v = make_float4(0.f, 0.f, 0.f, 0.f);
            if (gr < N_NODES) v = ((const float4*)nodes)[gr * 32 + c];
            *((float4*)&sm.As[r][c * 4]) = v;
        }
        __syncthreads();

        const int tx = t & 15;
        const int ty = t >> 4;
        const int r0 = ty * 4;

        float acc[4][8];
#pragma unroll
        for (int i = 0; i < 4; i++)
#pragma unroll
            for (int j = 0; j < 8; j++) acc[i][j] = 0.f;

        const float4* W4 = (const float4*)Wm;
#pragma unroll 4
        for (int k = 0; k < 128; k++) {
            float  a0 = sm.As[r0][k];
            float  a1 = sm.As[r0 + 1][k];
            float  a2 = sm.As[r0 + 2][k];
            float  a3 = sm.As[r0 + 3][k];
            float4 w0 = W4[k * 32 + tx * 2];
            float4 w1 = W4[k * 32 + tx * 2 + 1];
            float  wv[8] = {w0.x, w0.y, w0.z, w0.w, w1.x, w1.y, w1.z, w1.w};
#pragma unroll
            for (int j = 0; j < 8; j++) {
                acc[0][j] += a0 * wv[j];
                acc[1][j] += a1 * wv[j];
                acc[2][j] += a2 * wv[j];
                acc[3][j] += a3 * wv[j];
            }
        }

#pragma unroll
        for (int i = 0; i < 4; i++) {
            int gr = row0 + r0 + i;
            if (gr < N_NODES) {
                uint4 o;
                o.x = bf16pair(acc[i][0], acc[i][1]);
                o.y = bf16pair(acc[i][2], acc[i][3]);
                o.z = bf16pair(acc[i][4], acc[i][5]);
                o.w = bf16pair(acc[i][6], acc[i][7]);
                ((uint4*)Yb)[gr * 16 + tx] = o;    // 16 uint4 per 128-bf16 row
            }
        }
    } else {
        const int b = blockIdx.x - GEMM_BLOCKS;
        for (int n = t; n < N_NODES; n += 256) sm.cnt[n] = 0;
        __syncthreads();
        const int base = b * CHUNK;
        for (int i = t; i < CHUNK; i += 256) {
            int r = receivers[base + i];
            int s = senders[base + i];
            int l = atomicAdd(&sm.cnt[r], 1);          // LDS atomic: ns-latency
            pack[base + i] = (unsigned)s | ((unsigned)r << 14) | ((unsigned)l << 28);
        }
        __syncthreads();
        int* dst = bcnt + b * N_NODES;
        for (int n = t; n < N_NODES; n += 256) dst[n] = sm.cnt[n];
    }
}

// ---------------------------------------------------------------------------
// Kernel 2: column scan, 4 threads per node (R0-verified).
// ---------------------------------------------------------------------------
__global__ __launch_bounds__(256) void colscan_kernel(int* __restrict__ bcnt,
                                                      int* __restrict__ deg) {
    const int g = blockIdx.x * 256 + threadIdx.x;
    const int n = g >> 2;
    const int q = g & 3;
    if (n >= N_NODES) return;

    int pre[16];
    int s = 0;
#pragma unroll
    for (int j = 0; j < 16; j++) {
        int v = bcnt[(q * 16 + j) * N_NODES + n];
        pre[j] = s;
        s += v;
    }

    const int lane = threadIdx.x & 63;
    const int gb   = lane & ~3;          // group base lane
    int s0 = __shfl(s, gb + 0);
    int s1 = __shfl(s, gb + 1);
    int s2 = __shfl(s, gb + 2);
    int off = (q > 0 ? s0 : 0) + (q > 1 ? s1 : 0) + (q > 2 ? s2 : 0);

#pragma unroll
    for (int j = 0; j < 16; j++)
        bcnt[(q * 16 + j) * N_NODES + n] = off + pre[j];
    if (q == 3) deg[n] = off + s;
}

// ---------------------------------------------------------------------------
// Kernel 3: single-pass scatter into padded CSR (R5-phase-3 / R8 form;
// R8 showed XCD-partitioning vs single-pass is noise-equivalent, keep simple).
// ---------------------------------------------------------------------------
__global__ __launch_bounds__(256) void scatter_kernel(const unsigned* __restrict__ pack,
                                                      const int* __restrict__ bcnt,
                                                      int* __restrict__ csr) {
    const int i = blockIdx.x * 256 + threadIdx.x;    // 160000 uint4s exactly
    if (i >= N_EDGES / 4) return;
    const int b = i / (CHUNK / 4);                   // CHUNK%4==0: uint4 never straddles
    const int* pre = bcnt + b * N_NODES;
    uint4 p = ((const uint4*)pack)[i];
#pragma unroll
    for (int q = 0; q < 4; q++) {
        unsigned wd = (q == 0) ? p.x : (q == 1) ? p.y : (q == 2) ? p.z : p.w;
        int r = (int)((wd >> 14) & 0x3fffu);
        int s = (int)(wd & 0x3fffu);
        int l = (int)(wd >> 28);
        csr[(r << 8) + pre[r] + l] = s;
    }
}

// ---------------------------------------------------------------------------
// Kernel 4: reduction-free pull-gather (R3-verified). 16 lanes own one node.
// ---------------------------------------------------------------------------
__device__ inline void acc8(float* acc, uint4 v) {
    acc[0] += __uint_as_float(v.x << 16);
    acc[1] += __uint_as_float(v.x & 0xffff0000u);
    acc[2] += __uint_as_float(v.y << 16);
    acc[3] += __uint_as_float(v.y & 0xffff0000u);
    acc[4] += __uint_as_float(v.z << 16);
    acc[5] += __uint_as_float(v.z & 0xffff0000u);
    acc[6] += __uint_as_float(v.w << 16);
    acc[7] += __uint_as_float(v.w & 0xffff0000u);
}

__global__ __launch_bounds__(256) void gather_kernel(const unsigned* __restrict__ Yb,
                                                     const int* __restrict__ deg,
                                                     const int* __restrict__ csr,
                                                     const float* __restrict__ bias,
                                                     float* __restrict__ out) {
    const int t  = threadIdx.x;
    const int d4 = t & 15;                       // dim slot: 8 bf16 = 16 B
    const int n  = blockIdx.x * 16 + (t >> 4);   // grid = 625 -> exactly 10000

    const int dg   = deg[n];
    const int lim  = min(dg, PAD);
    const int base = n << 8;

    float acc[8];
#pragma unroll
    for (int k = 0; k < 8; k++) acc[k] = 0.f;

    const uint4* Y4 = (const uint4*)Yb;

    int j = 0;
    for (; j + 4 <= lim; j += 4) {
        int s0 = csr[base + j];
        int s1 = csr[base + j + 1];
        int s2 = csr[base + j + 2];
        int s3 = csr[base + j + 3];
        uint4 v0 = Y4[s0 * 16 + d4];
        uint4 v1 = Y4[s1 * 16 + d4];
        uint4 v2 = Y4[s2 * 16 + d4];
        uint4 v3 = Y4[s3 * 16 + d4];
        acc8(acc, v0);
        acc8(acc, v1);
        acc8(acc, v2);
        acc8(acc, v3);
    }
    for (; j < lim; j++) {
        int s = csr[base + j];
        acc8(acc, Y4[s * 16 + d4]);
    }

    const float inv = 1.0f / (float)max(dg, 1);
    float4 b0 = ((const float4*)bias)[d4 * 2];
    float4 b1 = ((const float4*)bias)[d4 * 2 + 1];
    float4 o0 = make_float4(acc[0] * inv + b0.x, acc[1] * inv + b0.y,
                            acc[2] * inv + b0.z, acc[3] * inv + b0.w);
    float4 o1 = make_float4(acc[4] * inv + b1.x, acc[5] * inv + b1.y,
                            acc[6] * inv + b1.z, acc[7] * inv + b1.w);
    ((float4*)&out[n * 128 + d4 * 8])[0] = o0;
    ((float4*)&out[n * 128 + d4 * 8])[1] = o1;
}

// ---------------------------------------------------------------------------
extern "C" void kernel_launch(void* const* d_in, const int* in_sizes, int n_in,
                              void* d_out, int out_size, void* d_ws, size_t ws_size,
                              hipStream_t stream) {
    const float* nodes     = (const float*)d_in[0];
    const int*   senders   = (const int*)  d_in[1];
    const int*   receivers = (const int*)  d_in[2];
    const float* Wm        = (const float*)d_in[3];
    const float* bias      = (const float*)d_in[4];
    float*       out       = (float*)d_out;

    // workspace layout (bytes)
    char*     w    = (char*)d_ws;
    unsigned* Yb   = (unsigned*)(w);               // bf16 Y:       2,560,000
    unsigned* pack = (unsigned*)(w + 2560000);     //               2,560,000
    int*      bcnt = (int*)(w + 5120000);          // 64x10000x4:   2,560,000
    int*      deg  = (int*)(w + 7680000);          //                  40,000
    int*      csr  = (int*)(w + 7720448);          // 10000x256x4: 10,240,000

    gemm_hist_kernel<<<NBLK, 256, 0, stream>>>(nodes, Wm, Yb,
                                               senders, receivers,
                                               pack, bcnt);
    colscan_kernel  <<<(4 * N_NODES + 255) / 256, 256, 0, stream>>>(bcnt, deg);
    scatter_kernel  <<<(N_EDGES / 4 + 255) / 256, 256, 0, stream>>>(pack, bcnt, csr);
    gather_kernel   <<<(N_NODES + 15) / 16, 256, 0, stream>>>(Yb, deg, csr, bias, out);
}